// Round 3
// baseline (656.385 us; speedup 1.0000x reference)
//
#include <hip/hip_runtime.h>
#include <hip/hip_bf16.h>

// Action_Prediction: 3-layer MLP (relu) -> scalar logit -> per-segment softmax
// -> Gumbel-max sample. N=524288, B=4096 segments of 128 contiguous nodes.
//
// R3: swapped MFMA operands (A=weights, B=rows) so the C/D lane layout holds
// 4 consecutive hidden-cols of one row -> packed b64 relu-writeback (was 128
// scalar b16 writes/wave). 512-thread blocks (16 waves/CU = 4/SIMD, occupancy
// 21%->~45%). Sampling fused into the epilogue (block == segment).
//
// d_ws: W0t bf16 [n=256][k=128], W1t [256][256], W2t [256][256] (N-major).

#define NFULL 524288
#define BSEG  4096
#define SEGSZ 128
#define DIN   128
#define HID   256
#define MROWS 128
#define KPAD  264   // LDS row stride (bf16 elems): 16B-aligned, bank-rotating

typedef __bf16 bf16x8 __attribute__((ext_vector_type(8)));
typedef float  f32x4  __attribute__((ext_vector_type(4)));

__device__ __forceinline__ unsigned short f2bf(float f) {
  __hip_bfloat16 h = __float2bfloat16(f);
  return __builtin_bit_cast(unsigned short, h);
}

// ------------------------------------------------- weight transpose+convert
__global__ __launch_bounds__(256) void convert_weights(
    const float* __restrict__ W0, const float* __restrict__ W1,
    const float* __restrict__ W2,
    unsigned short* __restrict__ W0t, unsigned short* __restrict__ W1t,
    unsigned short* __restrict__ W2t) {
  const int tid = blockIdx.x * 256 + threadIdx.x;
  if (tid < 32768) {                     // W0 [k=128][n=256] -> W0t[n][k]
    const int n = tid >> 7, k = tid & 127;
    W0t[tid] = f2bf(W0[k * 256 + n]);
  } else if (tid < 98304) {              // W1 [256][256]
    const int u = tid - 32768;
    const int n = u >> 8, k = u & 255;
    W1t[u] = f2bf(W1[k * 256 + n]);
  } else if (tid < 163840) {             // W2 [256][256]
    const int u = tid - 98304;
    const int n = u >> 8, k = u & 255;
    W2t[u] = f2bf(W2[k * 256 + n]);
  }
}

// --------------------------------------------------------- fused MLP+sample
// Block = 128 rows (one segment), 512 threads = 8 waves.
// Wave w: wq = w&3 -> cols [wq*64, +64); wr = w>>2 -> rows [wr*64, +64).
// acc[ct 4][rt 4] of 16x16 tiles. A-operand = weights Wt[n][k] (global, k-
// contiguous); B-operand = rows in LDS Abuf[row][k] (k-contiguous).
// D layout: lane&15 = row-in-tile, (lane>>4)*4+reg = col-in-tile.

template<int K>
__device__ __forceinline__ void do_layer(
    const unsigned short* Abuf, const unsigned short* __restrict__ Wt,
    const float* __restrict__ bias, int wq, int wr, int lane,
    f32x4 (&acc)[4][4]) {
  const int l15 = lane & 15;
  const int q   = lane >> 4;
  #pragma unroll
  for (int ct = 0; ct < 4; ++ct) {
    const float4 bv4 = *(const float4*)&bias[wq * 64 + ct * 16 + q * 4];
    f32x4 c; c[0] = bv4.x; c[1] = bv4.y; c[2] = bv4.z; c[3] = bv4.w;
    #pragma unroll
    for (int rt = 0; rt < 4; ++rt) acc[ct][rt] = c;
  }
  const unsigned short* Wb = Wt + (wq * 64 + l15) * K + q * 8;
  const unsigned short* Ab = Abuf + (wr * 64 + l15) * KPAD + q * 8;
  #pragma unroll 2
  for (int k0 = 0; k0 < K; k0 += 32) {
    bf16x8 wv[4], rv[4];
    #pragma unroll
    for (int ct = 0; ct < 4; ++ct)
      wv[ct] = *(const bf16x8*)(Wb + ct * 16 * K + k0);
    #pragma unroll
    for (int rt = 0; rt < 4; ++rt)
      rv[rt] = *(const bf16x8*)(Ab + rt * 16 * KPAD + k0);
    #pragma unroll
    for (int ct = 0; ct < 4; ++ct)
      #pragma unroll
      for (int rt = 0; rt < 4; ++rt)
        acc[ct][rt] = __builtin_amdgcn_mfma_f32_16x16x32_bf16(
            wv[ct], rv[rt], acc[ct][rt], 0, 0, 0);
  }
}

__device__ __forceinline__ void writeback_relu(
    unsigned short* Abuf, int wq, int wr, int lane, const f32x4 (&acc)[4][4]) {
  const int l15 = lane & 15, q = lane >> 4;
  #pragma unroll
  for (int rt = 0; rt < 4; ++rt) {
    const int row = wr * 64 + rt * 16 + l15;
    #pragma unroll
    for (int ct = 0; ct < 4; ++ct) {
      const int col = wq * 64 + ct * 16 + q * 4;
      ushort4 p;
      p.x = f2bf(fmaxf(acc[ct][rt][0], 0.f));
      p.y = f2bf(fmaxf(acc[ct][rt][1], 0.f));
      p.z = f2bf(fmaxf(acc[ct][rt][2], 0.f));
      p.w = f2bf(fmaxf(acc[ct][rt][3], 0.f));
      *(ushort4*)&Abuf[row * KPAD + col] = p;
    }
  }
}

__device__ __forceinline__ void threefry2x32_42(unsigned x0, unsigned x1,
                                                unsigned& o0, unsigned& o1) {
  const unsigned ks0 = 0u, ks1 = 42u;
  const unsigned ks2 = ks0 ^ ks1 ^ 0x1BD11BDAu;
  x0 += ks0; x1 += ks1;
#define TF_R(r) { x0 += x1; x1 = (x1 << (r)) | (x1 >> (32 - (r))); x1 ^= x0; }
  TF_R(13) TF_R(15) TF_R(26) TF_R(6)   x0 += ks1; x1 += ks2 + 1u;
  TF_R(17) TF_R(29) TF_R(16) TF_R(24)  x0 += ks2; x1 += ks0 + 2u;
  TF_R(13) TF_R(15) TF_R(26) TF_R(6)   x0 += ks0; x1 += ks1 + 3u;
  TF_R(17) TF_R(29) TF_R(16) TF_R(24)  x0 += ks1; x1 += ks2 + 4u;
  TF_R(13) TF_R(15) TF_R(26) TF_R(6)   x0 += ks2; x1 += ks0 + 5u;
#undef TF_R
  o0 = x0; o1 = x1;
}

__global__ __launch_bounds__(512, 4) void mlp_fused(
    const float* __restrict__ X,
    const unsigned short* __restrict__ W0t,
    const unsigned short* __restrict__ W1t,
    const unsigned short* __restrict__ W2t,
    const float* __restrict__ b0, const float* __restrict__ b1,
    const float* __restrict__ b2,
    const float* __restrict__ Wf, const float* __restrict__ bfp,
    float* __restrict__ out) {
  __shared__ alignas(16) unsigned short Abuf[MROWS * KPAD];  // 67.6 KB
  __shared__ float WfS[HID];
  __shared__ float Lpart[8][64];
  __shared__ float logit_sh[MROWS];
  __shared__ float red[2];
  __shared__ float smax_sh[2];
  __shared__ int   sidx_sh[2];
  const int tid  = threadIdx.x;
  const int lane = tid & 63;
  const int w    = tid >> 6;
  const int wq   = w & 3;       // col group
  const int wr   = w >> 2;      // row half
  const int l15  = lane & 15;
  const int q    = lane >> 4;
  const int seg  = blockIdx.x;
  const size_t row0 = (size_t)seg * MROWS;

  if (tid < HID) WfS[tid] = Wf[tid];

  // stage X (fp32 -> bf16): 128 rows x 32 float4 each = 4096 over 512 threads
  #pragma unroll
  for (int it = 0; it < 8; ++it) {
    const int idx = tid + it * 512;
    const int r   = idx >> 5;
    const int k4  = (idx & 31) * 4;
    const float4 v = *(const float4*)&X[(row0 + r) * DIN + k4];
    ushort4 p;
    p.x = f2bf(v.x); p.y = f2bf(v.y); p.z = f2bf(v.z); p.w = f2bf(v.w);
    *(ushort4*)&Abuf[r * KPAD + k4] = p;
  }
  __syncthreads();

  f32x4 acc[4][4];
  do_layer<DIN>(Abuf, W0t, b0, wq, wr, lane, acc);   // h0
  __syncthreads();
  writeback_relu(Abuf, wq, wr, lane, acc);
  __syncthreads();
  do_layer<HID>(Abuf, W1t, b1, wq, wr, lane, acc);   // h1
  __syncthreads();
  writeback_relu(Abuf, wq, wr, lane, acc);
  __syncthreads();
  do_layer<HID>(Abuf, W2t, b2, wq, wr, lane, acc);   // h2 pre-relu in regs

  // head: logit[row] = sum_col relu(h2[row][col]) * Wf[col] + bf
  {
    float part[4];
    #pragma unroll
    for (int rt = 0; rt < 4; ++rt) {
      float p = 0.f;
      #pragma unroll
      for (int ct = 0; ct < 4; ++ct) {
        const int col = wq * 64 + ct * 16 + q * 4;
        #pragma unroll
        for (int r = 0; r < 4; ++r)
          p = fmaf(fmaxf(acc[ct][rt][r], 0.f), WfS[col + r], p);
      }
      part[rt] = p;
    }
    #pragma unroll
    for (int rt = 0; rt < 4; ++rt) {
      part[rt] += __shfl_xor(part[rt], 16, 64);
      part[rt] += __shfl_xor(part[rt], 32, 64);
    }
    if (q == 0)
      #pragma unroll
      for (int rt = 0; rt < 4; ++rt) Lpart[w][rt * 16 + l15] = part[rt];
  }
  __syncthreads();
  if (tid < MROWS) {
    const int g = (tid >> 6) * 4;     // rows<64 -> waves 0..3, else 4..7
    const int r = tid & 63;
    logit_sh[tid] = Lpart[g][r] + Lpart[g + 1][r] + Lpart[g + 2][r] +
                    Lpart[g + 3][r] + bfp[0];
  }
  __syncthreads();

  // ---- fused sampling over the 128 in-LDS logits (threads 0..127) ----
  float e = 0.f, score = 0.f, prob = 0.f;
  if (tid < SEGSZ) {
    e = expf(logit_sh[tid]);
    float v = e;
    #pragma unroll
    for (int off = 32; off >= 1; off >>= 1) v += __shfl_xor(v, off, 64);
    if ((tid & 63) == 0) red[tid >> 6] = v;
  }
  __syncthreads();
  if (tid < SEGSZ) {
    const float S = red[0] + red[1];
    prob = e / S;
    unsigned o0, o1;
    threefry2x32_42(0u, (unsigned)(row0 + tid), o0, o1);
    const float f = __uint_as_float(0x3f800000u | (o0 >> 9)) - 1.0f;
    const float u = fmaxf(1e-20f, f + 1e-20f);
    const float g = -logf(-logf(u));
    score = logf(prob) + g;
    logit_sh[tid] = prob;            // reuse as probs_sh
    float ms = score; int mi = tid;
    #pragma unroll
    for (int off = 1; off < 64; off <<= 1) {
      const float os = __shfl_xor(ms, off, 64);
      const int   oi = __shfl_xor(mi, off, 64);
      if (os > ms || (os == ms && oi > mi)) { ms = os; mi = oi; }
    }
    if ((tid & 63) == 0) { smax_sh[tid >> 6] = ms; sidx_sh[tid >> 6] = mi; }
  }
  __syncthreads();
  if (tid == 0) {
    const float s0 = smax_sh[0], s1 = smax_sh[1];
    const int   i0 = sidx_sh[0], i1 = sidx_sh[1];
    const int win = (s1 > s0 || (s1 == s0 && i1 > i0)) ? i1 : i0;
    out[seg]            = logit_sh[win];             // p
    out[BSEG + seg]     = (float)win;                // action (local idx)
    out[2 * BSEG + seg] = (float)(row0 + win);       // shifted_action
  }
}

extern "C" void kernel_launch(void* const* d_in, const int* in_sizes, int n_in,
                              void* d_out, int out_size, void* d_ws, size_t ws_size,
                              hipStream_t stream) {
  const float* X  = (const float*)d_in[0];
  const float* W0 = (const float*)d_in[1];
  const float* b0 = (const float*)d_in[2];
  const float* W1 = (const float*)d_in[3];
  const float* b1 = (const float*)d_in[4];
  const float* W2 = (const float*)d_in[5];
  const float* b2 = (const float*)d_in[6];
  const float* Wf = (const float*)d_in[7];
  const float* bf = (const float*)d_in[8];

  unsigned short* W0t = (unsigned short*)d_ws;
  unsigned short* W1t = W0t + 256 * 128;
  unsigned short* W2t = W1t + 256 * 256;
  float* out = (float*)d_out;

  convert_weights<<<640, 256, 0, stream>>>(W0, W1, W2, W0t, W1t, W2t);
  mlp_fused<<<BSEG, 512, 0, stream>>>(X, W0t, W1t, W2t, b0, b1, b2,
                                      Wf, bf, out);
}

// Round 4
// 533.950 us; speedup vs baseline: 1.2293x; 1.2293x over previous
//
#include <hip/hip_runtime.h>
#include <hip/hip_bf16.h>

// Action_Prediction: 3-layer MLP (relu) -> scalar logit -> per-segment softmax
// -> Gumbel-max sample. N=524288, B=4096 segments of 128 contiguous nodes.
//
// R4: R2 wave shape (4 waves x [64 cols x 128 rows], 32 MFMA per k-step from
// 12 loads) + R3's swapped operands (packed b64 relu writeback) + fused
// sampling + coalesced-read convert kernel.  R3 post-mortem: 512-thread
// split-rows halved per-wave MFMA/load economy -> 281->417 µs regression;
// occupancy was not the binding constraint.
//
// d_ws: W0t bf16 [n=256][k=128], W1t [256][256], W2t [256][256] (N-major).

#define NFULL 524288
#define BSEG  4096
#define SEGSZ 128
#define DIN   128
#define HID   256
#define MROWS 128
#define KPAD  264   // LDS row stride (bf16 elems): 16B-aligned, bank-rotating

typedef __bf16 bf16x8 __attribute__((ext_vector_type(8)));
typedef float  f32x4  __attribute__((ext_vector_type(4)));

__device__ __forceinline__ unsigned short f2bf(float f) {
  __hip_bfloat16 h = __float2bfloat16(f);
  return __builtin_bit_cast(unsigned short, h);
}

// ------------------------------------------------- weight transpose+convert
// Coalesced fp32 reads (consecutive tid = consecutive source elements);
// bf16 stores scatter (posted writes, no stall).  R2/R3 version read with
// 1KB lane stride -> latency-serialized, ~200 µs of the total.
__global__ __launch_bounds__(256) void convert_weights(
    const float* __restrict__ W0, const float* __restrict__ W1,
    const float* __restrict__ W2,
    unsigned short* __restrict__ W0t, unsigned short* __restrict__ W1t,
    unsigned short* __restrict__ W2t) {
  const int tid = blockIdx.x * 256 + threadIdx.x;
  if (tid < 32768) {                     // W0 [k=128][n=256] row-major
    const int k = tid >> 8, n = tid & 255;
    W0t[n * 128 + k] = f2bf(W0[tid]);
  } else if (tid < 98304) {              // W1 [256][256]
    const int u = tid - 32768;
    const int k = u >> 8, n = u & 255;
    W1t[n * 256 + k] = f2bf(W1[u]);
  } else if (tid < 163840) {             // W2 [256][256]
    const int u = tid - 98304;
    const int k = u >> 8, n = u & 255;
    W2t[n * 256 + k] = f2bf(W2[u]);
  }
}

// --------------------------------------------------------- fused MLP+sample
// Block = 128 rows (one segment), 256 threads = 4 waves.
// Wave w: cols [w*64, +64) as A-operand (weights, 4 ct tiles), all 128 rows
// as B-operand from LDS (8 rt tiles).  acc[ct 4][rt 8].
// A-frag: A[m=lane&15][k=q*8+j] (m = weight col); B-frag: B[k][n=lane&15]
// (n = row).  D: lane&15 = row-in-tile, q*4+reg = col-in-tile -> packed
// ushort4 writeback.

template<int K>
__device__ __forceinline__ void do_layer(
    const unsigned short* Abuf, const unsigned short* __restrict__ Wt,
    const float* __restrict__ bias, int w, int lane, f32x4 (&acc)[4][8]) {
  const int l15 = lane & 15;
  const int q   = lane >> 4;
  #pragma unroll
  for (int ct = 0; ct < 4; ++ct) {
    const float4 bv4 = *(const float4*)&bias[w * 64 + ct * 16 + q * 4];
    f32x4 c; c[0] = bv4.x; c[1] = bv4.y; c[2] = bv4.z; c[3] = bv4.w;
    #pragma unroll
    for (int rt = 0; rt < 8; ++rt) acc[ct][rt] = c;
  }
  const unsigned short* Wb = Wt + (w * 64 + l15) * K + q * 8;
  const unsigned short* Ab = Abuf + l15 * KPAD + q * 8;
  #pragma unroll 2
  for (int k0 = 0; k0 < K; k0 += 32) {
    bf16x8 wv[4], rv[8];
    #pragma unroll
    for (int ct = 0; ct < 4; ++ct)
      wv[ct] = *(const bf16x8*)(Wb + ct * 16 * K + k0);
    #pragma unroll
    for (int rt = 0; rt < 8; ++rt)
      rv[rt] = *(const bf16x8*)(Ab + rt * 16 * KPAD + k0);
    #pragma unroll
    for (int ct = 0; ct < 4; ++ct)
      #pragma unroll
      for (int rt = 0; rt < 8; ++rt)
        acc[ct][rt] = __builtin_amdgcn_mfma_f32_16x16x32_bf16(
            wv[ct], rv[rt], acc[ct][rt], 0, 0, 0);
  }
}

__device__ __forceinline__ void writeback_relu(
    unsigned short* Abuf, int w, int lane, const f32x4 (&acc)[4][8]) {
  const int l15 = lane & 15, q = lane >> 4;
  #pragma unroll
  for (int rt = 0; rt < 8; ++rt) {
    const int row = rt * 16 + l15;
    #pragma unroll
    for (int ct = 0; ct < 4; ++ct) {
      const int col = w * 64 + ct * 16 + q * 4;
      ushort4 p;
      p.x = f2bf(fmaxf(acc[ct][rt][0], 0.f));
      p.y = f2bf(fmaxf(acc[ct][rt][1], 0.f));
      p.z = f2bf(fmaxf(acc[ct][rt][2], 0.f));
      p.w = f2bf(fmaxf(acc[ct][rt][3], 0.f));
      *(ushort4*)&Abuf[row * KPAD + col] = p;
    }
  }
}

__device__ __forceinline__ void threefry2x32_42(unsigned x0, unsigned x1,
                                                unsigned& o0, unsigned& o1) {
  const unsigned ks0 = 0u, ks1 = 42u;
  const unsigned ks2 = ks0 ^ ks1 ^ 0x1BD11BDAu;
  x0 += ks0; x1 += ks1;
#define TF_R(r) { x0 += x1; x1 = (x1 << (r)) | (x1 >> (32 - (r))); x1 ^= x0; }
  TF_R(13) TF_R(15) TF_R(26) TF_R(6)   x0 += ks1; x1 += ks2 + 1u;
  TF_R(17) TF_R(29) TF_R(16) TF_R(24)  x0 += ks2; x1 += ks0 + 2u;
  TF_R(13) TF_R(15) TF_R(26) TF_R(6)   x0 += ks0; x1 += ks1 + 3u;
  TF_R(17) TF_R(29) TF_R(16) TF_R(24)  x0 += ks1; x1 += ks2 + 4u;
  TF_R(13) TF_R(15) TF_R(26) TF_R(6)   x0 += ks2; x1 += ks0 + 5u;
#undef TF_R
  o0 = x0; o1 = x1;
}

__global__ __launch_bounds__(256, 2) void mlp_fused(
    const float* __restrict__ X,
    const unsigned short* __restrict__ W0t,
    const unsigned short* __restrict__ W1t,
    const unsigned short* __restrict__ W2t,
    const float* __restrict__ b0, const float* __restrict__ b1,
    const float* __restrict__ b2,
    const float* __restrict__ Wf, const float* __restrict__ bfp,
    float* __restrict__ out) {
  __shared__ alignas(16) unsigned short Abuf[MROWS * KPAD];  // 67.6 KB
  __shared__ float WfS[HID];
  __shared__ float Lpart[4][MROWS];
  __shared__ float logit_sh[MROWS];
  __shared__ float red[2];
  __shared__ float smax_sh[2];
  __shared__ int   sidx_sh[2];
  const int tid  = threadIdx.x;
  const int lane = tid & 63;
  const int w    = tid >> 6;
  const int l15  = lane & 15;
  const int q    = lane >> 4;
  const int seg  = blockIdx.x;
  const size_t row0 = (size_t)seg * MROWS;

  WfS[tid] = Wf[tid];

  // stage X (fp32 -> bf16): 128 rows x 32 float4 over 256 threads, 16 iters
  {
    const int k4 = (tid & 31) * 4;
    int r = tid >> 5;
    #pragma unroll
    for (int it = 0; it < 16; ++it, r += 8) {
      const float4 v = *(const float4*)&X[(row0 + r) * DIN + k4];
      ushort4 p;
      p.x = f2bf(v.x); p.y = f2bf(v.y); p.z = f2bf(v.z); p.w = f2bf(v.w);
      *(ushort4*)&Abuf[r * KPAD + k4] = p;
    }
  }
  __syncthreads();

  f32x4 acc[4][8];
  do_layer<DIN>(Abuf, W0t, b0, w, lane, acc);   // h0
  __syncthreads();
  writeback_relu(Abuf, w, lane, acc);
  __syncthreads();
  do_layer<HID>(Abuf, W1t, b1, w, lane, acc);   // h1
  __syncthreads();
  writeback_relu(Abuf, w, lane, acc);
  __syncthreads();
  do_layer<HID>(Abuf, W2t, b2, w, lane, acc);   // h2 pre-relu in regs

  // head: logit[row] = sum_col relu(h2[row][col]) * Wf[col] + bf
  {
    float part[8];
    #pragma unroll
    for (int rt = 0; rt < 8; ++rt) {
      float p = 0.f;
      #pragma unroll
      for (int ct = 0; ct < 4; ++ct) {
        const int col = w * 64 + ct * 16 + q * 4;
        #pragma unroll
        for (int r = 0; r < 4; ++r)
          p = fmaf(fmaxf(acc[ct][rt][r], 0.f), WfS[col + r], p);
      }
      part[rt] = p;
    }
    #pragma unroll
    for (int rt = 0; rt < 8; ++rt) {
      part[rt] += __shfl_xor(part[rt], 16, 64);
      part[rt] += __shfl_xor(part[rt], 32, 64);
    }
    if (q == 0)
      #pragma unroll
      for (int rt = 0; rt < 8; ++rt) Lpart[w][rt * 16 + l15] = part[rt];
  }
  __syncthreads();
  if (tid < MROWS)
    logit_sh[tid] = Lpart[0][tid] + Lpart[1][tid] + Lpart[2][tid] +
                    Lpart[3][tid] + bfp[0];
  __syncthreads();

  // ---- fused sampling over the 128 in-LDS logits (threads 0..127) ----
  float e = 0.f, prob = 0.f;
  if (tid < SEGSZ) {
    e = expf(logit_sh[tid]);
    float v = e;
    #pragma unroll
    for (int off = 32; off >= 1; off >>= 1) v += __shfl_xor(v, off, 64);
    if ((tid & 63) == 0) red[tid >> 6] = v;
  }
  __syncthreads();
  if (tid < SEGSZ) {
    const float S = red[0] + red[1];
    prob = e / S;
    unsigned o0, o1;
    threefry2x32_42(0u, (unsigned)(row0 + tid), o0, o1);
    const float f = __uint_as_float(0x3f800000u | (o0 >> 9)) - 1.0f;
    const float u = fmaxf(1e-20f, f + 1e-20f);
    const float g = -logf(-logf(u));
    const float score = logf(prob) + g;
    logit_sh[tid] = prob;            // reuse as probs_sh
    float ms = score; int mi = tid;
    #pragma unroll
    for (int off = 1; off < 64; off <<= 1) {
      const float os = __shfl_xor(ms, off, 64);
      const int   oi = __shfl_xor(mi, off, 64);
      if (os > ms || (os == ms && oi > mi)) { ms = os; mi = oi; }
    }
    if ((tid & 63) == 0) { smax_sh[tid >> 6] = ms; sidx_sh[tid >> 6] = mi; }
  }
  __syncthreads();
  if (tid == 0) {
    const float s0 = smax_sh[0], s1 = smax_sh[1];
    const int   i0 = sidx_sh[0], i1 = sidx_sh[1];
    const int win = (s1 > s0 || (s1 == s0 && i1 > i0)) ? i1 : i0;
    out[seg]            = logit_sh[win];             // p
    out[BSEG + seg]     = (float)win;                // action (local idx)
    out[2 * BSEG + seg] = (float)(row0 + win);       // shifted_action
  }
}

extern "C" void kernel_launch(void* const* d_in, const int* in_sizes, int n_in,
                              void* d_out, int out_size, void* d_ws, size_t ws_size,
                              hipStream_t stream) {
  const float* X  = (const float*)d_in[0];
  const float* W0 = (const float*)d_in[1];
  const float* b0 = (const float*)d_in[2];
  const float* W1 = (const float*)d_in[3];
  const float* b1 = (const float*)d_in[4];
  const float* W2 = (const float*)d_in[5];
  const float* b2 = (const float*)d_in[6];
  const float* Wf = (const float*)d_in[7];
  const float* bf = (const float*)d_in[8];

  unsigned short* W0t = (unsigned short*)d_ws;
  unsigned short* W1t = W0t + 256 * 128;
  unsigned short* W2t = W1t + 256 * 256;
  float* out = (float*)d_out;

  convert_weights<<<640, 256, 0, stream>>>(W0, W1, W2, W0t, W1t, W2t);
  mlp_fused<<<BSEG, 256, 0, stream>>>(X, W0t, W1t, W2t, b0, b1, b2,
                                      Wf, bf, out);
}